// Round 7
// baseline (524.466 us; speedup 1.0000x reference)
//
#include <hip/hip_runtime.h>

#define H 1024
#define W 1024
#define K 11
#define RAD 5
#define ROWS 64              /* R0 geometry: best redundancy (74/64=1.16) */
#define NIN (ROWS + K - 1)   /* 74 input rows per strip */
#define BW 256               /* columns per block (1 col/thread) */

typedef float v2f __attribute__((ext_vector_type(2)));

__global__ void zero_out_kernel(float* out) {
    if (threadIdx.x == 0) out[0] = 0.0f;
}

__device__ __forceinline__ float4 ld4u(const float* p) {
    float4 v;
    __builtin_memcpy(&v, p, sizeof(float4));
    return v;
}

__device__ __forceinline__ v2f pkfma(v2f a, v2f b, v2f c) {
    return __builtin_elementwise_fma(a, b, c);
}

template<bool FAST>
__device__ __forceinline__ void load_row(const float* __restrict__ r1,
                                         const float* __restrict__ r2,
                                         int col, float* x, float* y) {
    if (FAST) {
        const float* a1 = r1 + (col - RAD);
        const float* a2 = r2 + (col - RAD);
        float4 v0 = ld4u(a1), v1 = ld4u(a1 + 4), v2 = ld4u(a1 + 8);
        float4 u0 = ld4u(a2), u1 = ld4u(a2 + 4), u2 = ld4u(a2 + 8);
        x[0]=v0.x; x[1]=v0.y; x[2]=v0.z; x[3]=v0.w;
        x[4]=v1.x; x[5]=v1.y; x[6]=v1.z; x[7]=v1.w;
        x[8]=v2.x; x[9]=v2.y; x[10]=v2.z; x[11]=v2.w;
        y[0]=u0.x; y[1]=u0.y; y[2]=u0.z; y[3]=u0.w;
        y[4]=u1.x; y[5]=u1.y; y[6]=u1.z; y[7]=u1.w;
        y[8]=u2.x; y[9]=u2.y; y[10]=u2.z; y[11]=u2.w;
    } else {
        #pragma unroll
        for (int m = 0; m < 12; ++m) {
            const int gc = col - RAD + m;
            const bool ok = (unsigned)gc < (unsigned)W;
            x[m] = ok ? r1[gc] : 0.0f;
            y[m] = ok ? r2[gc] : 0.0f;
        }
    }
}

/* Vertical tap: slot S at phase P holds the row at distance d=(P-S+11)%11 from
   the newest; its weight is gw[10-d]. P,S are literals -> constant indices. */
#define SSIM_TAP(P,S) do {                                                    \
    const float w = gw[10 - ((P - S + 11) % 11)];                             \
    const v2f w2v = { w, w };                                                 \
    mu = pkfma(w2v, q##S, mu);                                                \
    sq = pkfma(w2v, t##S, sq);                                                \
    xy = fmaf(w, u##S, xy);                                                   \
} while (0)

/* One BRANCHLESS row-phase. No `i<NIN` guard (loop is peeled so every emitted
   phase is valid) — this is the point: with no control flow between phases the
   scheduler can hoist phase P+1's global loads above phase P's s_waitcnt,
   giving each load a full phase (~360 cyc x waves/SIMD) to land. DOOUT is a
   literal 0/1 (folds). ROWSAFE (template param) drops row clamp+mask for
   interior blocks. Ring state stays in NAMED regs (R2 lesson). */
#define SSIM_PHASE_NG(P, DOOUT) do {                                          \
    const int i = base + (P);                                                 \
    int rr; float sm;                                                         \
    if (ROWSAFE) {                                                            \
        rr = rin0 + i; sm = 1.0f;                                             \
    } else {                                                                  \
        const int r = rin0 + i;                                               \
        rr = min(max(r, 0), H - 1);                                           \
        sm = ((unsigned)r < (unsigned)H) ? 1.0f : 0.0f;                       \
    }                                                                         \
    float x[12], y[12];                                                       \
    load_row<FAST>(p1 + (size_t)rr * W, p2 + (size_t)rr * W, col, x, y);      \
    v2f amx = {0.f,0.f}, amy = {0.f,0.f};                                     \
    v2f axx = {0.f,0.f}, ayy = {0.f,0.f}, axy = {0.f,0.f};                    \
    _Pragma("unroll")                                                         \
    for (int e = 0; e < 5; ++e) {                                             \
        v2f w2 = { gw[2*e], gw[2*e+1] };                                      \
        v2f xp = { x[2*e], x[2*e+1] };                                        \
        v2f yp = { y[2*e], y[2*e+1] };                                        \
        v2f wxp = w2 * xp;                                                    \
        v2f wyp = w2 * yp;                                                    \
        amx += wxp; amy += wyp;                                               \
        axx = pkfma(wxp, xp, axx);                                            \
        ayy = pkfma(wyp, yp, ayy);                                            \
        axy = pkfma(wxp, yp, axy);                                            \
    }                                                                         \
    const float twx = gw[10] * x[10];                                         \
    const float twy = gw[10] * y[10];                                         \
    const float hmx = (amx.x + amx.y) + twx;                                  \
    const float hmy = (amy.x + amy.y) + twy;                                  \
    const float hxx = fmaf(twx, x[10], axx.x + axx.y);                        \
    const float hyy = fmaf(twy, y[10], ayy.x + ayy.y);                        \
    const float hxy = fmaf(twx, y[10], axy.x + axy.y);                        \
    if (ROWSAFE) {                                                            \
        q##P = (v2f){ hmx, hmy };                                             \
        t##P = (v2f){ hxx, hyy };                                             \
        u##P = hxy;                                                           \
    } else {                                                                  \
        const v2f sv = { sm, sm };                                            \
        q##P = sv * (v2f){ hmx, hmy };                                        \
        t##P = sv * (v2f){ hxx, hyy };                                        \
        u##P = sm * hxy;                                                      \
    }                                                                         \
    if (DOOUT) {                                                              \
        v2f mu = {0.f,0.f}, sq = {0.f,0.f}; float xy = 0.f;                   \
        SSIM_TAP(P,0); SSIM_TAP(P,1); SSIM_TAP(P,2); SSIM_TAP(P,3);           \
        SSIM_TAP(P,4); SSIM_TAP(P,5); SSIM_TAP(P,6); SSIM_TAP(P,7);           \
        SSIM_TAP(P,8); SSIM_TAP(P,9); SSIM_TAP(P,10);                         \
        const v2f m2 = mu * mu;                                               \
        const float mxy  = mu.x * mu.y;                                       \
        const v2f sg = sq - m2;                                               \
        const float sxyv = xy - mxy;                                          \
        const float num = fmaf(2.0f, mxy,  C1) * fmaf(2.0f, sxyv, C2);        \
        const float den = (m2.x + m2.y + C1) * (sg.x + sg.y + C2);            \
        acc += num * __builtin_amdgcn_rcpf(den);                              \
    }                                                                         \
} while (0)

template<bool FAST, bool ROWSAFE>
__device__ __forceinline__ float run_strip(const float* __restrict__ p1,
                                           const float* __restrict__ p2,
                                           int col, int rin0, const float* gw) {
    // Ring in 33 NAMED registers (no arrays -> no scratch across the backedge).
    const v2f z2 = {0.f, 0.f};
    v2f q0=z2,q1=z2,q2=z2,q3=z2,q4=z2,q5=z2,q6=z2,q7=z2,q8=z2,q9=z2,q10=z2;
    v2f t0=z2,t1=z2,t2=z2,t3=z2,t4=z2,t5=z2,t6=z2,t7=z2,t8=z2,t9=z2,t10=z2;
    float u0=0,u1=0,u2=0,u3=0,u4=0,u5=0,u6=0,u7=0,u8=0,u9=0,u10=0;
    float acc = 0.0f;
    const float C1 = 1e-4f;
    const float C2 = 9e-4f;

    // Peeled 74 = 11 (warm-up) + 5*11 (hot rolled loop) + 8 (tail).
    // Every phase everywhere is branchless.
    {   // warm-up: rows 0..10; first output at phase 10
        const int base = 0;
        SSIM_PHASE_NG(0,0); SSIM_PHASE_NG(1,0); SSIM_PHASE_NG(2,0);
        SSIM_PHASE_NG(3,0); SSIM_PHASE_NG(4,0); SSIM_PHASE_NG(5,0);
        SSIM_PHASE_NG(6,0); SSIM_PHASE_NG(7,0); SSIM_PHASE_NG(8,0);
        SSIM_PHASE_NG(9,0); SSIM_PHASE_NG(10,1);
    }
    #pragma unroll 1
    for (int it = 1; it < 6; ++it) {   // hot body: rows 11..65, I$-resident
        const int base = it * K;
        SSIM_PHASE_NG(0,1);  SSIM_PHASE_NG(1,1);  SSIM_PHASE_NG(2,1);
        SSIM_PHASE_NG(3,1);  SSIM_PHASE_NG(4,1);  SSIM_PHASE_NG(5,1);
        SSIM_PHASE_NG(6,1);  SSIM_PHASE_NG(7,1);  SSIM_PHASE_NG(8,1);
        SSIM_PHASE_NG(9,1);  SSIM_PHASE_NG(10,1);
    }
    {   // tail: rows 66..73 (66 % 11 == 0, so slot/tap literals line up)
        const int base = 66;
        SSIM_PHASE_NG(0,1);  SSIM_PHASE_NG(1,1);  SSIM_PHASE_NG(2,1);
        SSIM_PHASE_NG(3,1);  SSIM_PHASE_NG(4,1);  SSIM_PHASE_NG(5,1);
        SSIM_PHASE_NG(6,1);  SSIM_PHASE_NG(7,1);
    }
    return acc;
}

__launch_bounds__(256, 2)
__global__ void ssim_kernel(const float* __restrict__ img1,
                            const float* __restrict__ img2,
                            const float* __restrict__ kern,
                            float* __restrict__ out,
                            float inv_n) {
    __shared__ float wsum[4];

    const int tid = threadIdx.x;
    const int col = blockIdx.x * BW + tid;
    const int ry0 = blockIdx.y * ROWS;
    const int b   = blockIdx.z;

    // 1D gaussian = row sums of normalized 2D kernel (exact). Pin to SGPRs.
    float gw[K];
    #pragma unroll
    for (int t = 0; t < K; ++t) {
        float s = 0.0f;
        #pragma unroll
        for (int j = 0; j < K; ++j) s += kern[t * K + j];
        gw[t] = __int_as_float(__builtin_amdgcn_readfirstlane(__float_as_int(s)));
    }

    const float* __restrict__ p1 = img1 + (size_t)b * H * W;
    const float* __restrict__ p2 = img2 + (size_t)b * H * W;
    const int rin0 = ry0 - RAD;

    // Block-uniform row-safety: interior by (1..14) never clamps/masks rows.
    const bool rowsafe = (rin0 >= 0) && (rin0 + NIN <= H);
    // Wave-uniform fast/slow split: fast iff ALL lanes' 12-col windows in-bounds.
    const bool colfast = (col >= RAD) && (col + RAD + 1 < W);
    const unsigned long long bal = __ballot(colfast);

    float acc;
    if (bal == ~0ULL) {
        acc = rowsafe ? run_strip<true,  true >(p1, p2, col, rin0, gw)
                      : run_strip<true,  false>(p1, p2, col, rin0, gw);
    } else {
        acc = rowsafe ? run_strip<false, true >(p1, p2, col, rin0, gw)
                      : run_strip<false, false>(p1, p2, col, rin0, gw);
    }

    // Wave butterfly reduce -> cross-wave via LDS -> one atomic per block.
    for (int off = 32; off > 0; off >>= 1)
        acc += __shfl_down(acc, off, 64);
    if ((tid & 63) == 0) wsum[tid >> 6] = acc;
    __syncthreads();
    if (tid == 0) {
        const float s = wsum[0] + wsum[1] + wsum[2] + wsum[3];
        atomicAdd(out, s * inv_n);
    }
}

extern "C" void kernel_launch(void* const* d_in, const int* in_sizes, int n_in,
                              void* d_out, int out_size, void* d_ws, size_t ws_size,
                              hipStream_t stream) {
    const float* img1 = (const float*)d_in[0];
    const float* img2 = (const float*)d_in[1];
    const float* kern = (const float*)d_in[2];
    float* out = (float*)d_out;

    const int B = in_sizes[0] / (H * W);
    const float inv_n = 1.0f / ((float)B * (float)H * (float)W);

    zero_out_kernel<<<dim3(1), dim3(64), 0, stream>>>(out);

    dim3 grid(W / BW, H / ROWS, B);
    ssim_kernel<<<grid, dim3(256), 0, stream>>>(img1, img2, kern, out, inv_n);
}

// Round 8
// 255.051 us; speedup vs baseline: 2.0563x; 2.0563x over previous
//
#include <hip/hip_runtime.h>

#define H 1024
#define W 1024
#define K 11
#define RAD 5
#define ROWS 64              /* R0 geometry: best redundancy (74/64=1.16) */
#define NIN (ROWS + K - 1)   /* 74 input rows per strip */
#define BW 256               /* columns per block (1 col/thread) */

typedef float v2f __attribute__((ext_vector_type(2)));

__global__ void zero_out_kernel(float* out) {
    if (threadIdx.x == 0) out[0] = 0.0f;
}

__device__ __forceinline__ float4 ld4u(const float* p) {
    float4 v;
    __builtin_memcpy(&v, p, sizeof(float4));
    return v;
}

__device__ __forceinline__ v2f pkfma(v2f a, v2f b, v2f c) {
    return __builtin_elementwise_fma(a, b, c);
}

// Load the 12-float window [col-5, col+7) of both images into SIX NAMED float4s
// (the 1-deep pipeline registers — exactly 24 VGPRs of lookahead, bounded by
// construction; R7 showed unbounded compiler lookahead spills).
template<bool FAST>
__device__ __forceinline__ void load6(const float* __restrict__ r1,
                                      const float* __restrict__ r2, int col,
                                      float4& a0, float4& a1, float4& a2,
                                      float4& b0, float4& b1, float4& b2) {
    if (FAST) {
        const float* a = r1 + (col - RAD);
        const float* b = r2 + (col - RAD);
        a0 = ld4u(a); a1 = ld4u(a + 4); a2 = ld4u(a + 8);
        b0 = ld4u(b); b1 = ld4u(b + 4); b2 = ld4u(b + 8);
    } else {
        float x[12], y[12];
        #pragma unroll
        for (int m = 0; m < 12; ++m) {
            const int gc = col - RAD + m;
            const bool ok = (unsigned)gc < (unsigned)W;
            x[m] = ok ? r1[gc] : 0.0f;
            y[m] = ok ? r2[gc] : 0.0f;
        }
        a0 = make_float4(x[0], x[1], x[2],  x[3]);
        a1 = make_float4(x[4], x[5], x[6],  x[7]);
        a2 = make_float4(x[8], x[9], x[10], x[11]);
        b0 = make_float4(y[0], y[1], y[2],  y[3]);
        b1 = make_float4(y[4], y[5], y[6],  y[7]);
        b2 = make_float4(y[8], y[9], y[10], y[11]);
    }
}

/* Vertical tap: slot S at phase P holds the row at distance d=(P-S+11)%11 from
   the newest; its weight is gw[10-d]. P,S are literals -> constant indices. */
#define SSIM_TAP(P,S) do {                                                    \
    const float w = gw[10 - ((P - S + 11) % 11)];                             \
    const v2f w2v = { w, w };                                                 \
    mu = pkfma(w2v, q##S, mu);                                                \
    sq = pkfma(w2v, t##S, sq);                                                \
    xy = fmaf(w, u##S, xy);                                                   \
} while (0)

/* One GUARDED row-phase with manual 1-deep prefetch:
   consume pipeline regs (row i, loaded at phase i-1) -> issue row i+1 loads ->
   compute. The guard stays (R7: removing it let the scheduler hoist unboundedly
   -> 175 MB scratch). Load->use distance = one full phase (~100 instrs). Ring
   state and pipeline regs are NAMED vars (R2 lesson: no arrays across the
   backedge). ROWSAFE (template literal) drops row clamp/mask for the 14/16
   interior strips. */
#define SSIM_PHASE_PF(P) do {                                                 \
    const int i = base + (P);                                                 \
    if (i < NIN) {                                                            \
        /* consume the in-flight row (SSA rename, no real copies) */          \
        const float x[12] = {na0.x,na0.y,na0.z,na0.w,                         \
                             na1.x,na1.y,na1.z,na1.w,                         \
                             na2.x,na2.y,na2.z,na2.w};                        \
        const float y[12] = {nb0.x,nb0.y,nb0.z,nb0.w,                         \
                             nb1.x,nb1.y,nb1.z,nb1.w,                         \
                             nb2.x,nb2.y,nb2.z,nb2.w};                        \
        /* issue next row's loads into the pipeline regs */                   \
        {                                                                     \
            int rn = rin0 + i + 1;                                            \
            rn = ROWSAFE ? min(rn, H - 1) : min(max(rn, 0), H - 1);           \
            load6<FAST>(p1 + (size_t)rn * W, p2 + (size_t)rn * W, col,        \
                        na0, na1, na2, nb0, nb1, nb2);                        \
        }                                                                     \
        v2f amx = {0.f,0.f}, amy = {0.f,0.f};                                 \
        v2f axx = {0.f,0.f}, ayy = {0.f,0.f}, axy = {0.f,0.f};                \
        _Pragma("unroll")                                                     \
        for (int e = 0; e < 5; ++e) {                                         \
            v2f w2 = { gw[2*e], gw[2*e+1] };                                  \
            v2f xp = { x[2*e], x[2*e+1] };                                    \
            v2f yp = { y[2*e], y[2*e+1] };                                    \
            v2f wxp = w2 * xp;                                                \
            v2f wyp = w2 * yp;                                                \
            amx += wxp; amy += wyp;                                           \
            axx = pkfma(wxp, xp, axx);                                        \
            ayy = pkfma(wyp, yp, ayy);                                        \
            axy = pkfma(wxp, yp, axy);                                        \
        }                                                                     \
        const float twx = gw[10] * x[10];                                     \
        const float twy = gw[10] * y[10];                                     \
        const float hmx = (amx.x + amx.y) + twx;                              \
        const float hmy = (amy.x + amy.y) + twy;                              \
        const float hxx = fmaf(twx, x[10], axx.x + axx.y);                    \
        const float hyy = fmaf(twy, y[10], ayy.x + ayy.y);                    \
        const float hxy = fmaf(twx, y[10], axy.x + axy.y);                    \
        if (ROWSAFE) {                                                        \
            q##P = (v2f){ hmx, hmy };                                         \
            t##P = (v2f){ hxx, hyy };                                         \
            u##P = hxy;                                                       \
        } else {                                                              \
            const int r = rin0 + i;                                           \
            const float sm = ((unsigned)r < (unsigned)H) ? 1.0f : 0.0f;       \
            const v2f sv = { sm, sm };                                        \
            q##P = sv * (v2f){ hmx, hmy };                                    \
            t##P = sv * (v2f){ hxx, hyy };                                    \
            u##P = sm * hxy;                                                  \
        }                                                                     \
        if (i >= K - 1) {                                                     \
            v2f mu = {0.f,0.f}, sq = {0.f,0.f}; float xy = 0.f;               \
            SSIM_TAP(P,0); SSIM_TAP(P,1); SSIM_TAP(P,2); SSIM_TAP(P,3);       \
            SSIM_TAP(P,4); SSIM_TAP(P,5); SSIM_TAP(P,6); SSIM_TAP(P,7);       \
            SSIM_TAP(P,8); SSIM_TAP(P,9); SSIM_TAP(P,10);                     \
            const v2f m2 = mu * mu;                                           \
            const float mxy  = mu.x * mu.y;                                   \
            const v2f sg = sq - m2;                                           \
            const float sxyv = xy - mxy;                                      \
            const float num = fmaf(2.0f, mxy,  C1) * fmaf(2.0f, sxyv, C2);    \
            const float den = (m2.x + m2.y + C1) * (sg.x + sg.y + C2);        \
            acc += num * __builtin_amdgcn_rcpf(den);                          \
        }                                                                     \
    }                                                                         \
} while (0)

template<bool FAST, bool ROWSAFE>
__device__ __forceinline__ float run_strip(const float* __restrict__ p1,
                                           const float* __restrict__ p2,
                                           int col, int rin0, const float* gw) {
    // Ring in 33 NAMED registers (no arrays -> no scratch across the backedge).
    const v2f z2 = {0.f, 0.f};
    v2f q0=z2,q1=z2,q2=z2,q3=z2,q4=z2,q5=z2,q6=z2,q7=z2,q8=z2,q9=z2,q10=z2;
    v2f t0=z2,t1=z2,t2=z2,t3=z2,t4=z2,t5=z2,t6=z2,t7=z2,t8=z2,t9=z2,t10=z2;
    float u0=0,u1=0,u2=0,u3=0,u4=0,u5=0,u6=0,u7=0,u8=0,u9=0,u10=0;
    float acc = 0.0f;
    const float C1 = 1e-4f;
    const float C2 = 9e-4f;

    // 1-deep pipeline registers (named float4s = bounded 24-VGPR lookahead).
    float4 na0, na1, na2, nb0, nb1, nb2;
    {   // prologue: load strip row 0
        const int r0 = min(max(rin0, 0), H - 1);
        load6<FAST>(p1 + (size_t)r0 * W, p2 + (size_t)r0 * W, col,
                    na0, na1, na2, nb0, nb1, nb2);
    }

    // ROLLED outer loop (R6 win: hot body I$-resident), guarded phases.
    #pragma unroll 1
    for (int it = 0; it < 7; ++it) {
        const int base = it * K;
        SSIM_PHASE_PF(0);  SSIM_PHASE_PF(1);  SSIM_PHASE_PF(2);
        SSIM_PHASE_PF(3);  SSIM_PHASE_PF(4);  SSIM_PHASE_PF(5);
        SSIM_PHASE_PF(6);  SSIM_PHASE_PF(7);  SSIM_PHASE_PF(8);
        SSIM_PHASE_PF(9);  SSIM_PHASE_PF(10);
    }
    return acc;
}

__launch_bounds__(256, 2)
__global__ void ssim_kernel(const float* __restrict__ img1,
                            const float* __restrict__ img2,
                            const float* __restrict__ kern,
                            float* __restrict__ out,
                            float inv_n) {
    __shared__ float wsum[4];

    const int tid = threadIdx.x;
    const int col = blockIdx.x * BW + tid;
    const int ry0 = blockIdx.y * ROWS;
    const int b   = blockIdx.z;

    // 1D gaussian = row sums of normalized 2D kernel (exact). Pin to SGPRs.
    float gw[K];
    #pragma unroll
    for (int t = 0; t < K; ++t) {
        float s = 0.0f;
        #pragma unroll
        for (int j = 0; j < K; ++j) s += kern[t * K + j];
        gw[t] = __int_as_float(__builtin_amdgcn_readfirstlane(__float_as_int(s)));
    }

    const float* __restrict__ p1 = img1 + (size_t)b * H * W;
    const float* __restrict__ p2 = img2 + (size_t)b * H * W;
    const int rin0 = ry0 - RAD;

    // Block-uniform row-safety: interior by (1..14) never clamps/masks rows.
    const bool rowsafe = (rin0 >= 0) && (rin0 + NIN <= H);
    // Wave-uniform fast/slow split: fast iff ALL lanes' 12-col windows in-bounds.
    const bool colfast = (col >= RAD) && (col + RAD + 1 < W);
    const unsigned long long bal = __ballot(colfast);

    float acc;
    if (bal == ~0ULL) {
        acc = rowsafe ? run_strip<true,  true >(p1, p2, col, rin0, gw)
                      : run_strip<true,  false>(p1, p2, col, rin0, gw);
    } else {
        acc = rowsafe ? run_strip<false, true >(p1, p2, col, rin0, gw)
                      : run_strip<false, false>(p1, p2, col, rin0, gw);
    }

    // Wave butterfly reduce -> cross-wave via LDS -> one atomic per block.
    for (int off = 32; off > 0; off >>= 1)
        acc += __shfl_down(acc, off, 64);
    if ((tid & 63) == 0) wsum[tid >> 6] = acc;
    __syncthreads();
    if (tid == 0) {
        const float s = wsum[0] + wsum[1] + wsum[2] + wsum[3];
        atomicAdd(out, s * inv_n);
    }
}

extern "C" void kernel_launch(void* const* d_in, const int* in_sizes, int n_in,
                              void* d_out, int out_size, void* d_ws, size_t ws_size,
                              hipStream_t stream) {
    const float* img1 = (const float*)d_in[0];
    const float* img2 = (const float*)d_in[1];
    const float* kern = (const float*)d_in[2];
    float* out = (float*)d_out;

    const int B = in_sizes[0] / (H * W);
    const float inv_n = 1.0f / ((float)B * (float)H * (float)W);

    zero_out_kernel<<<dim3(1), dim3(64), 0, stream>>>(out);

    dim3 grid(W / BW, H / ROWS, B);
    ssim_kernel<<<grid, dim3(256), 0, stream>>>(img1, img2, kern, out, inv_n);
}

// Round 9
// 196.870 us; speedup vs baseline: 2.6640x; 1.2955x over previous
//
#include <hip/hip_runtime.h>

#define H 1024
#define W 1024
#define K 11
#define RAD 5
#define ROWS 64              /* 74/64 = 1.16 redundancy (R0-proven best) */
#define NIN (ROWS + K - 1)   /* 74 input rows per strip */
#define BW 256               /* output cols per block (1 col/thread) */
#define SW 272               /* staged floats per row per image (267 used, padded) */

typedef float v2f __attribute__((ext_vector_type(2)));

__global__ void zero_out_kernel(float* out) {
    if (threadIdx.x == 0) out[0] = 0.0f;
}

__device__ __forceinline__ v2f pkfma(v2f a, v2f b, v2f c) {
    return __builtin_elementwise_fma(a, b, c);
}

/* Vertical tap: slot S at phase P holds the row at distance d=(P-S+11)%11 from
   the newest; weight gw[10-d]. P,S literals -> constant indices. */
#define SSIM_TAP(P,S) do {                                                    \
    const float w = gw[10 - ((P - S + 11) % 11)];                             \
    const v2f w2v = { w, w };                                                 \
    mu = pkfma(w2v, q##S, mu);                                                \
    sq = pkfma(w2v, t##S, sq);                                                \
    xy = fmaf(w, u##S, xy);                                                   \
} while (0)

/* One row-phase, LDS-staged:
   1. issue row i+1 global loads (1 guarded dword/img/thread; SGPR row base)
   2. read row i windows from LDS buf[i&1] (11 consecutive b32/img: conflict-free)
   3. compute (R6 body)
   4. vmcnt wait lands HERE (after ~250cyc compute) -> ds_write row i+1 to
      buf[(i+1)&1]; barrier.
   Pipeline state lives in LDS, not registers -> no copies (R8 failure), no
   spill (R7 failure). Guard `i<NIN` is block-uniform -> barrier-safe. */
#define SSIM_PHASE_LDS(P) do {                                                \
    const int i = base + (P);                                                 \
    if (i < NIN) {                                                            \
        /* ---- 1. global prefetch of row i+1 ---- */                         \
        float g1m, g2m, g1t = 0.f, g2t = 0.f;                                 \
        {                                                                     \
            int rn = rin0 + i + 1;                                            \
            rn = min(max(rn, 0), H - 1);                                      \
            const float* __restrict__ r1 = p1 + (size_t)rn * W;               \
            const float* __restrict__ r2 = p2 + (size_t)rn * W;               \
            g1m = r1[gmc] * okm;                                              \
            g2m = r2[gmc] * okm;                                              \
            if (tid < 11) { g1t = r1[gtc] * okt; g2t = r2[gtc] * okt; }       \
        }                                                                     \
        /* ---- 2. window of row i from LDS ---- */                           \
        const float* __restrict__ sA = bufA + (i & 1) * (2 * SW);             \
        const float* __restrict__ sB = sA + SW;                               \
        float x[11], y[11];                                                   \
        _Pragma("unroll")                                                     \
        for (int j = 0; j < 11; ++j) { x[j] = sA[tid + j]; y[j] = sB[tid + j]; } \
        /* ---- 3a. horizontal 11-tap, tap-paired packed fp32 ---- */         \
        v2f amx = {0.f,0.f}, amy = {0.f,0.f};                                 \
        v2f axx = {0.f,0.f}, ayy = {0.f,0.f}, axy = {0.f,0.f};                \
        _Pragma("unroll")                                                     \
        for (int e = 0; e < 5; ++e) {                                         \
            v2f w2 = { gw[2*e], gw[2*e+1] };                                  \
            v2f xp = { x[2*e], x[2*e+1] };                                    \
            v2f yp = { y[2*e], y[2*e+1] };                                    \
            v2f wxp = w2 * xp;                                                \
            v2f wyp = w2 * yp;                                                \
            amx += wxp; amy += wyp;                                           \
            axx = pkfma(wxp, xp, axx);                                        \
            ayy = pkfma(wyp, yp, ayy);                                        \
            axy = pkfma(wxp, yp, axy);                                        \
        }                                                                     \
        const float twx = gw[10] * x[10];                                     \
        const float twy = gw[10] * y[10];                                     \
        const float hmx = (amx.x + amx.y) + twx;                              \
        const float hmy = (amy.x + amy.y) + twy;                              \
        const float hxx = fmaf(twx, x[10], axx.x + axx.y);                    \
        const float hyy = fmaf(twy, y[10], ayy.x + ayy.y);                    \
        const float hxy = fmaf(twx, y[10], axy.x + axy.y);                    \
        {                                                                     \
            const int r = rin0 + i;                                           \
            const float sm = ((unsigned)r < (unsigned)H) ? 1.0f : 0.0f;       \
            const v2f sv = { sm, sm };                                        \
            q##P = sv * (v2f){ hmx, hmy };                                    \
            t##P = sv * (v2f){ hxx, hyy };                                    \
            u##P = sm * hxy;                                                  \
        }                                                                     \
        /* ---- 3b. vertical 11-tap + SSIM ---- */                            \
        if (i >= K - 1) {                                                     \
            v2f mu = {0.f,0.f}, sq = {0.f,0.f}; float xy = 0.f;               \
            SSIM_TAP(P,0); SSIM_TAP(P,1); SSIM_TAP(P,2); SSIM_TAP(P,3);       \
            SSIM_TAP(P,4); SSIM_TAP(P,5); SSIM_TAP(P,6); SSIM_TAP(P,7);       \
            SSIM_TAP(P,8); SSIM_TAP(P,9); SSIM_TAP(P,10);                     \
            const v2f m2 = mu * mu;                                           \
            const float mxy  = mu.x * mu.y;                                   \
            const v2f sg = sq - m2;                                           \
            const float sxyv = xy - mxy;                                      \
            const float num = fmaf(2.0f, mxy,  C1) * fmaf(2.0f, sxyv, C2);    \
            const float den = (m2.x + m2.y + C1) * (sg.x + sg.y + C2);        \
            acc += num * __builtin_amdgcn_rcpf(den);                          \
        }                                                                     \
        /* ---- 4. stage row i+1 into the other buffer ---- */                \
        float* __restrict__ dA = bufA + ((i + 1) & 1) * (2 * SW);             \
        float* __restrict__ dB = dA + SW;                                     \
        dA[tid] = g1m;                                                        \
        dB[tid] = g2m;                                                        \
        if (tid < 11) { dA[256 + tid] = g1t; dB[256 + tid] = g2t; }           \
        __syncthreads();                                                      \
    }                                                                         \
} while (0)

__launch_bounds__(256, 3)
__global__ void ssim_kernel(const float* __restrict__ img1,
                            const float* __restrict__ img2,
                            const float* __restrict__ kern,
                            float* __restrict__ out,
                            float inv_n) {
    __shared__ float sbuf[2][2][SW];   /* [parity][img][col] = 4352 B */
    __shared__ float wsum[4];
    float* bufA = &sbuf[0][0][0];

    const int tid = threadIdx.x;
    const int cb  = blockIdx.x * BW;
    const int ry0 = blockIdx.y * ROWS;
    const int b   = blockIdx.z;

    // 1D gaussian = row sums of normalized 2D kernel (exact). Pin to SGPRs.
    float gw[K];
    #pragma unroll
    for (int t = 0; t < K; ++t) {
        float s = 0.0f;
        #pragma unroll
        for (int j = 0; j < K; ++j) s += kern[t * K + j];
        gw[t] = __int_as_float(__builtin_amdgcn_readfirstlane(__float_as_int(s)));
    }

    const float* __restrict__ p1 = img1 + (size_t)b * H * W;
    const float* __restrict__ p2 = img2 + (size_t)b * H * W;
    const int rin0 = ry0 - RAD;

    // Staging indices: main covers LDS[0..255] <- col cb-5+tid; tail (tid<11)
    // covers LDS[256..266] <- col cb+251+tid. Column edges masked at stage ->
    // NO fast/slow or rowsafe code splits anywhere (one path, smaller I$).
    const int  gmc_raw = cb - 5 + tid;
    const float okm = ((unsigned)gmc_raw < (unsigned)W) ? 1.0f : 0.0f;
    const int  gmc = min(max(gmc_raw, 0), W - 1);
    const int  gtc_raw = cb + 251 + tid;
    const float okt = ((unsigned)gtc_raw < (unsigned)W) ? 1.0f : 0.0f;
    const int  gtc = min(gtc_raw, W - 1);

    // Ring in 33 NAMED registers (R2 lesson: no arrays across the backedge).
    const v2f z2 = {0.f, 0.f};
    v2f q0=z2,q1=z2,q2=z2,q3=z2,q4=z2,q5=z2,q6=z2,q7=z2,q8=z2,q9=z2,q10=z2;
    v2f t0=z2,t1=z2,t2=z2,t3=z2,t4=z2,t5=z2,t6=z2,t7=z2,t8=z2,t9=z2,t10=z2;
    float u0=0,u1=0,u2=0,u3=0,u4=0,u5=0,u6=0,u7=0,u8=0,u9=0,u10=0;
    float acc = 0.0f;
    const float C1 = 1e-4f;
    const float C2 = 9e-4f;

    {   // prologue: stage strip row 0 into buf 0
        const int r0 = min(max(rin0, 0), H - 1);
        const float* __restrict__ r1 = p1 + (size_t)r0 * W;
        const float* __restrict__ r2 = p2 + (size_t)r0 * W;
        sbuf[0][0][tid] = r1[gmc] * okm;
        sbuf[0][1][tid] = r2[gmc] * okm;
        if (tid < 11) {
            sbuf[0][0][256 + tid] = r1[gtc] * okt;
            sbuf[0][1][256 + tid] = r2[gtc] * okt;
        }
        __syncthreads();
    }

    // ROLLED outer loop (R6 win: ~11KB hot body, I$-resident), guarded phases.
    #pragma unroll 1
    for (int it = 0; it < 7; ++it) {
        const int base = it * K;
        SSIM_PHASE_LDS(0);  SSIM_PHASE_LDS(1);  SSIM_PHASE_LDS(2);
        SSIM_PHASE_LDS(3);  SSIM_PHASE_LDS(4);  SSIM_PHASE_LDS(5);
        SSIM_PHASE_LDS(6);  SSIM_PHASE_LDS(7);  SSIM_PHASE_LDS(8);
        SSIM_PHASE_LDS(9);  SSIM_PHASE_LDS(10);
    }

    // Wave butterfly reduce -> cross-wave via LDS -> one atomic per block.
    for (int off = 32; off > 0; off >>= 1)
        acc += __shfl_down(acc, off, 64);
    if ((tid & 63) == 0) wsum[tid >> 6] = acc;
    __syncthreads();
    if (tid == 0) {
        const float s = wsum[0] + wsum[1] + wsum[2] + wsum[3];
        atomicAdd(out, s * inv_n);
    }
}

extern "C" void kernel_launch(void* const* d_in, const int* in_sizes, int n_in,
                              void* d_out, int out_size, void* d_ws, size_t ws_size,
                              hipStream_t stream) {
    const float* img1 = (const float*)d_in[0];
    const float* img2 = (const float*)d_in[1];
    const float* kern = (const float*)d_in[2];
    float* out = (float*)d_out;

    const int B = in_sizes[0] / (H * W);
    const float inv_n = 1.0f / ((float)B * (float)H * (float)W);

    zero_out_kernel<<<dim3(1), dim3(64), 0, stream>>>(out);

    dim3 grid(W / BW, H / ROWS, B);
    ssim_kernel<<<grid, dim3(256), 0, stream>>>(img1, img2, kern, out, inv_n);
}

// Round 12
// 195.234 us; speedup vs baseline: 2.6864x; 1.0084x over previous
//
#include <hip/hip_runtime.h>

#define H 1024
#define W 1024
#define K 11
#define RAD 5
#define ROWS 64              /* 74/64 = 1.16 redundancy (R0-proven best) */
#define NIN (ROWS + K - 1)   /* 74 input rows per strip */
#define BW 256               /* output cols per block (1 col/thread) */
#define SW 272               /* staged floats per row per image (267 used, padded) */

typedef float v2f __attribute__((ext_vector_type(2)));

__global__ void zero_out_kernel(float* out) {
    if (threadIdx.x == 0) out[0] = 0.0f;
}

__device__ __forceinline__ v2f pkfma(v2f a, v2f b, v2f c) {
    return __builtin_elementwise_fma(a, b, c);
}

/* Vertical tap: slot S at phase P holds the row at distance d=(P-S+11)%11 from
   the newest; weight gw[10-d]. P,S literals -> constant indices. */
#define SSIM_TAP(P,S) do {                                                    \
    const float w = gw[10 - ((P - S + 11) % 11)];                             \
    const v2f w2v = { w, w };                                                 \
    mu = pkfma(w2v, q##S, mu);                                                \
    sq = pkfma(w2v, t##S, sq);                                                \
    xy = fmaf(w, u##S, xy);                                                   \
} while (0)

/* One row-phase, LDS-staged with a TWO-ROW-DEEP global pipeline:
   1. issue row i+2 global loads -> 'n' regs (4 named scalars, bounded)
   2. read row i windows from LDS buf[i&1]
   3. compute (R6 body)
   4. ds_write row i+1 from 'h' regs (loaded at phase i-1 -> the vmcnt wait
      here is ~2 full phases (~800cyc) after issue, covering HBM latency;
      R9's 1-deep version exposed the latency tail at every phase); barrier;
      rename h <- n.
   Pipeline state: LDS (row windows) + 8 named VGPRs (in-flight rows). No
   arrays across the backedge (R2), no unbounded lookahead (R7). */
#define SSIM_PHASE_LDS2(P) do {                                               \
    const int i = base + (P);                                                 \
    if (i < NIN) {                                                            \
        /* ---- 1. issue global loads of row i+2 ---- */                      \
        float n1m, n2m, n1t = 0.f, n2t = 0.f;                                 \
        {                                                                     \
            int rn = rin0 + i + 2;                                            \
            rn = min(max(rn, 0), H - 1);                                      \
            const float* __restrict__ r1 = p1 + (size_t)rn * W;               \
            const float* __restrict__ r2 = p2 + (size_t)rn * W;               \
            n1m = r1[gmc] * okm;                                              \
            n2m = r2[gmc] * okm;                                              \
            if (tid < 11) { n1t = r1[gtc] * okt; n2t = r2[gtc] * okt; }       \
        }                                                                     \
        /* ---- 2. window of row i from LDS ---- */                           \
        const float* __restrict__ sA = bufA + (i & 1) * (2 * SW);             \
        const float* __restrict__ sB = sA + SW;                               \
        float x[11], y[11];                                                   \
        _Pragma("unroll")                                                     \
        for (int j = 0; j < 11; ++j) { x[j] = sA[tid + j]; y[j] = sB[tid + j]; } \
        /* ---- 3a. horizontal 11-tap, tap-paired packed fp32 ---- */         \
        v2f amx = {0.f,0.f}, amy = {0.f,0.f};                                 \
        v2f axx = {0.f,0.f}, ayy = {0.f,0.f}, axy = {0.f,0.f};                \
        _Pragma("unroll")                                                     \
        for (int e = 0; e < 5; ++e) {                                         \
            v2f w2 = { gw[2*e], gw[2*e+1] };                                  \
            v2f xp = { x[2*e], x[2*e+1] };                                    \
            v2f yp = { y[2*e], y[2*e+1] };                                    \
            v2f wxp = w2 * xp;                                                \
            v2f wyp = w2 * yp;                                                \
            amx += wxp; amy += wyp;                                           \
            axx = pkfma(wxp, xp, axx);                                        \
            ayy = pkfma(wyp, yp, ayy);                                        \
            axy = pkfma(wxp, yp, axy);                                        \
        }                                                                     \
        const float twx = gw[10] * x[10];                                     \
        const float twy = gw[10] * y[10];                                     \
        const float hmx = (amx.x + amx.y) + twx;                              \
        const float hmy = (amy.x + amy.y) + twy;                              \
        const float hxx = fmaf(twx, x[10], axx.x + axx.y);                    \
        const float hyy = fmaf(twy, y[10], ayy.x + ayy.y);                    \
        const float hxy = fmaf(twx, y[10], axy.x + axy.y);                    \
        {                                                                     \
            const int r = rin0 + i;                                           \
            const float sm = ((unsigned)r < (unsigned)H) ? 1.0f : 0.0f;       \
            const v2f sv = { sm, sm };                                        \
            q##P = sv * (v2f){ hmx, hmy };                                    \
            t##P = sv * (v2f){ hxx, hyy };                                    \
            u##P = sm * hxy;                                                  \
        }                                                                     \
        /* ---- 3b. vertical 11-tap + SSIM ---- */                            \
        if (i >= K - 1) {                                                     \
            v2f mu = {0.f,0.f}, sq = {0.f,0.f}; float xy = 0.f;               \
            SSIM_TAP(P,0); SSIM_TAP(P,1); SSIM_TAP(P,2); SSIM_TAP(P,3);       \
            SSIM_TAP(P,4); SSIM_TAP(P,5); SSIM_TAP(P,6); SSIM_TAP(P,7);       \
            SSIM_TAP(P,8); SSIM_TAP(P,9); SSIM_TAP(P,10);                     \
            const v2f m2 = mu * mu;                                           \
            const float mxy  = mu.x * mu.y;                                   \
            const v2f sg = sq - m2;                                           \
            const float sxyv = xy - mxy;                                      \
            const float num = fmaf(2.0f, mxy,  C1) * fmaf(2.0f, sxyv, C2);    \
            const float den = (m2.x + m2.y + C1) * (sg.x + sg.y + C2);        \
            acc += num * __builtin_amdgcn_rcpf(den);                          \
        }                                                                     \
        /* ---- 4. stage row i+1 (held regs) into the other buffer ---- */    \
        float* __restrict__ dA = bufA + ((i + 1) & 1) * (2 * SW);             \
        float* __restrict__ dB = dA + SW;                                     \
        dA[tid] = h1m;                                                        \
        dB[tid] = h2m;                                                        \
        if (tid < 11) { dA[256 + tid] = h1t; dB[256 + tid] = h2t; }           \
        __syncthreads();                                                      \
        h1m = n1m; h2m = n2m; h1t = n1t; h2t = n2t;                           \
    }                                                                         \
} while (0)

__launch_bounds__(256, 3)
__global__ void ssim_kernel(const float* __restrict__ img1,
                            const float* __restrict__ img2,
                            const float* __restrict__ kern,
                            float* __restrict__ out,
                            float inv_n) {
    __shared__ float sbuf[2][2][SW];   /* [parity][img][col] = 4352 B */
    __shared__ float wsum[4];
    float* bufA = &sbuf[0][0][0];

    const int tid = threadIdx.x;
    const int cb  = blockIdx.x * BW;
    const int ry0 = blockIdx.y * ROWS;
    const int b   = blockIdx.z;

    // 1D gaussian = row sums of normalized 2D kernel (exact). Pin to SGPRs.
    float gw[K];
    #pragma unroll
    for (int t = 0; t < K; ++t) {
        float s = 0.0f;
        #pragma unroll
        for (int j = 0; j < K; ++j) s += kern[t * K + j];
        gw[t] = __int_as_float(__builtin_amdgcn_readfirstlane(__float_as_int(s)));
    }

    const float* __restrict__ p1 = img1 + (size_t)b * H * W;
    const float* __restrict__ p2 = img2 + (size_t)b * H * W;
    const int rin0 = ry0 - RAD;

    // Staging indices: main covers LDS[0..255] <- col cb-5+tid; tail (tid<11)
    // covers LDS[256..266] <- col cb+251+tid. Column edges masked at stage ->
    // no fast/slow or rowsafe splits anywhere (one path, small I$ body).
    const int  gmc_raw = cb - 5 + tid;
    const float okm = ((unsigned)gmc_raw < (unsigned)W) ? 1.0f : 0.0f;
    const int  gmc = min(max(gmc_raw, 0), W - 1);
    const int  gtc_raw = cb + 251 + tid;
    const float okt = ((unsigned)gtc_raw < (unsigned)W) ? 1.0f : 0.0f;
    const int  gtc = min(gtc_raw, W - 1);

    // Ring in 33 NAMED registers (R2 lesson: no arrays across the backedge).
    const v2f z2 = {0.f, 0.f};
    v2f q0=z2,q1=z2,q2=z2,q3=z2,q4=z2,q5=z2,q6=z2,q7=z2,q8=z2,q9=z2,q10=z2;
    v2f t0=z2,t1=z2,t2=z2,t3=z2,t4=z2,t5=z2,t6=z2,t7=z2,t8=z2,t9=z2,t10=z2;
    float u0=0,u1=0,u2=0,u3=0,u4=0,u5=0,u6=0,u7=0,u8=0,u9=0,u10=0;
    float acc = 0.0f;
    const float C1 = 1e-4f;
    const float C2 = 9e-4f;

    // 2-deep pipeline hold regs (row i+1's values during phase i).
    float h1m, h2m, h1t = 0.f, h2t = 0.f;

    {   // prologue: stage strip row 0 into buf 0; load row 1 into hold regs
        const int r0 = min(max(rin0, 0), H - 1);
        const float* __restrict__ r1 = p1 + (size_t)r0 * W;
        const float* __restrict__ r2 = p2 + (size_t)r0 * W;
        sbuf[0][0][tid] = r1[gmc] * okm;
        sbuf[0][1][tid] = r2[gmc] * okm;
        if (tid < 11) {
            sbuf[0][0][256 + tid] = r1[gtc] * okt;
            sbuf[0][1][256 + tid] = r2[gtc] * okt;
        }
        const int rn = min(max(rin0 + 1, 0), H - 1);
        const float* __restrict__ s1 = p1 + (size_t)rn * W;
        const float* __restrict__ s2 = p2 + (size_t)rn * W;
        h1m = s1[gmc] * okm;
        h2m = s2[gmc] * okm;
        if (tid < 11) { h1t = s1[gtc] * okt; h2t = s2[gtc] * okt; }
        __syncthreads();
    }

    // ROLLED outer loop (R6 win: ~11KB hot body, I$-resident), guarded phases.
    #pragma unroll 1
    for (int it = 0; it < 7; ++it) {
        const int base = it * K;
        SSIM_PHASE_LDS2(0);  SSIM_PHASE_LDS2(1);  SSIM_PHASE_LDS2(2);
        SSIM_PHASE_LDS2(3);  SSIM_PHASE_LDS2(4);  SSIM_PHASE_LDS2(5);
        SSIM_PHASE_LDS2(6);  SSIM_PHASE_LDS2(7);  SSIM_PHASE_LDS2(8);
        SSIM_PHASE_LDS2(9);  SSIM_PHASE_LDS2(10);
    }

    // Wave butterfly reduce -> cross-wave via LDS -> one atomic per block.
    for (int off = 32; off > 0; off >>= 1)
        acc += __shfl_down(acc, off, 64);
    if ((tid & 63) == 0) wsum[tid >> 6] = acc;
    __syncthreads();
    if (tid == 0) {
        const float s = wsum[0] + wsum[1] + wsum[2] + wsum[3];
        atomicAdd(out, s * inv_n);
    }
}

extern "C" void kernel_launch(void* const* d_in, const int* in_sizes, int n_in,
                              void* d_out, int out_size, void* d_ws, size_t ws_size,
                              hipStream_t stream) {
    const float* img1 = (const float*)d_in[0];
    const float* img2 = (const float*)d_in[1];
    const float* kern = (const float*)d_in[2];
    float* out = (float*)d_out;

    const int B = in_sizes[0] / (H * W);
    const float inv_n = 1.0f / ((float)B * (float)H * (float)W);

    zero_out_kernel<<<dim3(1), dim3(64), 0, stream>>>(out);

    dim3 grid(W / BW, H / ROWS, B);
    ssim_kernel<<<grid, dim3(256), 0, stream>>>(img1, img2, kern, out, inv_n);
}